// Round 13
// baseline (376.287 us; speedup 1.0000x reference)
//
#include <hip/hip_runtime.h>
#include <math.h>

typedef __bf16 bf16;
typedef __bf16 bf16x4 __attribute__((ext_vector_type(4)));
typedef __bf16 bf16x8 __attribute__((ext_vector_type(8)));
typedef float f32x4 __attribute__((ext_vector_type(4)));
typedef unsigned short u16;
typedef u16 u16x2 __attribute__((ext_vector_type(2)));

#define LOG2E 1.4426950408889634f

__device__ __forceinline__ float b2f(u16 b) {
  return (float)__builtin_bit_cast(bf16, b);
}

// ---------------------------------------------------------------------------
// dtype sniff (wave-parallel): packed-bf16 words have bits14..7 = bf16
// exponent (~[118,130]); f32 words have uniform mantissa bits there.
// ---------------------------------------------------------------------------
__global__ void sniff_k(const unsigned* __restrict__ xw_, int* __restrict__ flag) {
  int lane = threadIdx.x;  // 64 threads
  int c = 0;
#pragma unroll
  for (int j = 0; j < 4; j++) {
    unsigned e = (xw_[lane * 4 + j] >> 7) & 0xFFu;
    c += (e >= 100u && e <= 140u) ? 1 : 0;
  }
#pragma unroll
  for (int d = 1; d < 64; d <<= 1) c += __shfl_xor(c, d);
  if (lane == 0) *flag = (c >= 150) ? 1 : 0;
}

// canon g1/b1n ahead of pro_k (pro_k's ln1 segment consumes them; intra-
// kernel block ordering is undefined, so they must be ready beforehand).
__global__ __launch_bounds__(256) void canon_norm_k(
    const void* __restrict__ sg, const void* __restrict__ sb,
    bf16* __restrict__ dg, bf16* __restrict__ db, const int* __restrict__ flag) {
  int i = threadIdx.x;  // 256 threads, 128 elems each tensor
  int fl = *flag;
  if (i < 128) {
    dg[i] = fl ? ((const bf16*)sg)[i] : (bf16)((const float*)sg)[i];
  } else {
    int j = i - 128;
    db[j] = fl ? ((const bf16*)sb)[j] : (bf16)((const float*)sb)[j];
  }
}

// ---------------------------------------------------------------------------
// Fused prologue: one launch, three block-segments:
//   [0,8192)      rpem: fused rpe+mask planes, PERMUTED layout, RAW rel_bias
//   [8192,24576)  ln1: LN + roll(-4) + window partition, RAW input
//   [24576,27648) canon: 12 small weight tensors -> bf16
// rpem plane[type][h] is [kt:8][quad:4][q:512][mt:4][r:4]; value =
// rel_bias[rel_index[q*512+m]][h]*log2e + (masked?-100*log2e:0).
// ---------------------------------------------------------------------------
struct ProArgs {
  const int* ridx;
  const void* rbias;
  bf16* rpem;
  const void* x;
  const bf16* g1;
  const bf16* b1n;
  bf16* xw;
  const void* csrc[12];
  bf16* cdst[12];
  int cn[12];
};

__global__ __launch_bounds__(256) void pro_k(ProArgs a,
                                             const int* __restrict__ flag) {
  const int bx = blockIdx.x, tid = threadIdx.x;
  const int fl = *flag;
  if (bx < 8192) {  // ---- rpem ----
    int t = bx * 256 + tid;  // 2^21 threads, 4 m-values each
    int m0 = (t & 127) * 4, q = (t >> 7) & 511, h = (t >> 16) & 3, ty = t >> 18;
    int qd = q >> 6, qh = (q >> 3) & 7, qw = q & 7;
    int kt = m0 >> 6, mt = (m0 >> 4) & 3, quad = (m0 >> 2) & 3;
    int4 ri = *(const int4*)&a.ridx[q * 512 + m0];
    const int rv[4] = {ri.x, ri.y, ri.z, ri.w};
    bf16x4 o;
#pragma unroll
    for (int j = 0; j < 4; j++) {
      int m = m0 + j;
      int md = m >> 6, mh = (m >> 3) & 7, mw = m & 7;
      bool diff = ((ty & 4) && ((qd < 4) != (md < 4))) ||
                  ((ty & 2) && ((qh < 4) != (mh < 4))) ||
                  ((ty & 1) && ((qw < 4) != (mw < 4)));
      float bv = fl ? (float)((const bf16*)a.rbias)[rv[j] * 4 + h]
                    : ((const float*)a.rbias)[rv[j] * 4 + h];
      float v = bv * LOG2E;
      o[j] = (bf16)(v + (diff ? -144.2695041f : 0.f));
    }
    size_t out = ((size_t)(ty * 4 + h) << 18) +
                 (((size_t)(kt * 4 + quad) * 512 + q) * 16 + mt * 4);
    *(bf16x4*)&a.rpem[out] = o;
  } else if (bx < 24576) {  // ---- ln1 (roll + window partition) ----
    int wave = tid >> 6, lane = tid & 63;
    int tok = (bx - 8192) * 4 + wave;
    int win = tok >> 9, pos = tok & 511;
    int rd = (win >> 6) * 8 + (pos >> 6);
    int rh = ((win >> 3) & 7) * 8 + ((pos >> 3) & 7);
    int rw = (win & 7) * 8 + (pos & 7);
    int od = (rd + 4) & 15, oh = (rh + 4) & 63, ow = (rw + 4) & 63;
    size_t src = (size_t)((od * 64 + oh) * 64 + ow) * 128;
    int ch = lane * 2;
    float f0, f1;
    if (!fl) {
      const float* xf = (const float*)a.x + src + ch;
      f0 = xf[0];
      f1 = xf[1];
    } else {
      u16x2 xv = *(const u16x2*)((const bf16*)a.x + src + ch);
      f0 = b2f(xv[0]);
      f1 = b2f(xv[1]);
    }
    float s = f0 + f1, sq = f0 * f0 + f1 * f1;
#pragma unroll
    for (int d = 1; d < 64; d <<= 1) {
      s += __shfl_xor(s, d);
      sq += __shfl_xor(sq, d);
    }
    float mean = s * (1.f / 128.f);
    float var = sq * (1.f / 128.f) - mean * mean;
    float rstd = rsqrtf(fmaxf(var, 0.f) + 1e-5f);
    u16x2 gv = *(const u16x2*)(a.g1 + ch), bv = *(const u16x2*)(a.b1n + ch);
    u16x2 ov;
    ov[0] =
        __builtin_bit_cast(u16, (bf16)((f0 - mean) * rstd * b2f(gv[0]) + b2f(bv[0])));
    ov[1] =
        __builtin_bit_cast(u16, (bf16)((f1 - mean) * rstd * b2f(gv[1]) + b2f(bv[1])));
    *(u16x2*)(a.xw + (size_t)tok * 128 + ch) = ov;
  } else {  // ---- canon ----
    int seg = bx - 24576;
    int ti = seg >> 8;
    int i = (seg & 255) * 256 + tid;
    if (i < a.cn[ti]) {
      if (fl)
        a.cdst[ti][i] = ((const bf16*)a.csrc[ti])[i];
      else
        a.cdst[ti][i] = (bf16)((const float*)a.csrc[ti])[i];
    }
  }
}

// ---------------------------------------------------------------------------
// bf16 MFMA GEMM: C[M,N] = A[M,K] @ B[N,K]^T + bias[N] (+ epilogue)
// BM=32, BK=128 single-stage, LDS 40 KB -> 4 blocks/CU. global_load_lds
// width=16, linear LDS dest, inverse-XOR-swizzled global source, XOR on
// ds_read. Direct-store epilogue.
// EPI: 0 = qkv (q scale*log2e, head-major scatter), 1 = proj (win-rev+roll+
//      RAW-resid via flag)
// ---------------------------------------------------------------------------
template <int EPI, int BM, int BK, int N_, int K_>
__global__ __launch_bounds__(256) void gemm_k(const bf16* __restrict__ A,
                                              const bf16* __restrict__ B,
                                              const bf16* __restrict__ bias,
                                              void* __restrict__ outv,
                                              const void* __restrict__ residv,
                                              const int* __restrict__ flag) {
  constexpr int NC = K_ / BK;
  constexpr int NBUF = (NC > 1) ? 2 : 1;
  __shared__ __align__(16) u16 SM[NBUF][(BM + 128) * BK];
  const int t = threadIdx.x;
  const int wave = t >> 6, lane = t & 63, l15 = lane & 15, quad = lane >> 4;
  const int m0 = blockIdx.x * BM, n0 = blockIdx.y * 128;
  constexpr int MI = BM / 32;  // m-frags per wave
  int fl = 0;
  if constexpr (EPI == 1) fl = *flag;
  f32x4 acc[MI][4] = {};
  const int wr = (wave >> 1) * (BM / 2), wc = (wave & 1) * 64;
  constexpr int TPR = BK / 8;     // 16B chunks per row
  constexpr int RPP = 256 / TPR;  // rows staged per 256-thread pass
  constexpr int PASSES = (BM + 128) / RPP;
  const int srow = t / TPR, sc16 = t % TPR;

  auto stage = [&](int c, int buf) {
#pragma unroll
    for (int p = 0; p < PASSES; p++) {
      int row = p * RPP + srow;
      int cs = sc16 ^ (row & 7);
      const u16* src;
      if (row < BM)
        src = (const u16*)A + (size_t)(m0 + row) * K_ + c * BK + cs * 8;
      else
        src = (const u16*)B + (size_t)(n0 + row - BM) * K_ + c * BK + cs * 8;
      __builtin_amdgcn_global_load_lds(
          (const __attribute__((address_space(1))) void*)src,
          (__attribute__((address_space(3))) void*)&SM[buf][row * BK + sc16 * 8],
          16, 0, 0);
    }
  };

  stage(0, 0);
  __syncthreads();  // vmcnt(0) drain + barrier: buf0 fully staged
#pragma unroll
  for (int c = 0; c < NC; c++) {
    if (c + 1 < NC) stage(c + 1, (c + 1) & 1);
    const char* cur = (const char*)SM[c & 1];
#pragma unroll
    for (int ks = 0; ks < BK / 32; ks++) {
      bf16x8 a[MI], b[4];
#pragma unroll
      for (int i = 0; i < MI; i++) {
        int row = wr + i * 16 + l15;
        a[i] = *(const bf16x8*)(cur + row * (BK * 2) +
                                (((ks * 4 + quad) ^ (row & 7)) << 4));
      }
#pragma unroll
      for (int j = 0; j < 4; j++) {
        int row = BM + wc + j * 16 + l15;
        b[j] = *(const bf16x8*)(cur + row * (BK * 2) +
                                (((ks * 4 + quad) ^ (row & 7)) << 4));
      }
#pragma unroll
      for (int i = 0; i < MI; i++)
#pragma unroll
        for (int j = 0; j < 4; j++)
          acc[i][j] =
              __builtin_amdgcn_mfma_f32_16x16x32_bf16(a[i], b[j], acc[i][j], 0, 0, 0);
    }
    if (c + 1 < NC) __syncthreads();
  }
  // q scale folded with log2e for exp2-domain softmax downstream
  const float qscale = 0.17677669529663687f * LOG2E;
#pragma unroll
  for (int i = 0; i < MI; i++) {
#pragma unroll
    for (int r = 0; r < 4; r++) {
      int tok = m0 + wr + i * 16 + quad * 4 + r;
      size_t obase = 0;
      if constexpr (EPI == 1) {
        int win = tok >> 9, pos = tok & 511;
        int rd = (win >> 6) * 8 + (pos >> 6);
        int rh = ((win >> 3) & 7) * 8 + ((pos >> 3) & 7);
        int rw = (win & 7) * 8 + (pos & 7);
        int od = (rd + 4) & 15, oh = (rh + 4) & 63, ow = (rw + 4) & 63;
        obase = (size_t)((od * 64 + oh) * 64 + ow) * 128;
      }
#pragma unroll
      for (int j = 0; j < 4; j++) {
        int gn = n0 + wc + j * 16 + l15;
        float v = acc[i][j][r] + (float)bias[gn];
        if constexpr (EPI == 0) {
          int tensor = gn >> 7, c = gn & 127, head = c >> 5, d = c & 31;
          if (tensor == 0) v *= qscale;
          int win = tok >> 9, pos = tok & 511;
          size_t off = ((((size_t)tensor * 4 + head) * 128 + win) * 512 + pos) * 32 + d;
          ((bf16*)outv)[off] = (bf16)v;
        } else {
          float rs = fl ? (float)((const bf16*)residv)[obase + gn]
                        : ((const float*)residv)[obase + gn];
          v += rs;
          ((bf16*)outv)[obase + gn] = (bf16)v;
        }
      }
    }
  }
}

// ---------------------------------------------------------------------------
// Fused MLP (R13): R10 structure + T14 register-staged W prefetch: next W
// chunk is loaded into 8 named bf16x8 regs (inline, constant-indexed — the
// form that worked in gemm R1; NOT R4's lambda form) BEFORE the compute
// phase, then ds_written after the barrier. Same chunk size, same barrier
// count — only the global latency moves off the critical path. 256 thr,
// LDS 73 KB -> 2 blocks/CU (VGPR headroom ample).
// ---------------------------------------------------------------------------
__global__ __launch_bounds__(256) void mlp_k(const bf16* __restrict__ X2,
                                             const bf16* __restrict__ G2,
                                             const bf16* __restrict__ B2n,
                                             const bf16* __restrict__ W1,
                                             const bf16* __restrict__ B1,
                                             const bf16* __restrict__ W2,
                                             const bf16* __restrict__ B2,
                                             void* __restrict__ outv,
                                             const int* __restrict__ flag) {
  __shared__ __align__(16) u16 sA[32 * 128];   // LN(x2) tile, swizzled, 8 KB
  __shared__ __align__(16) u16 sB[128 * 128];  // w1/w2 chunk, swizzled, 32 KB
  __shared__ __align__(16) u16 sH[32 * 520];   // gelu(h1) tile, padded, 33 KB
  const int t = threadIdx.x;
  const int wave = t >> 6, lane = t & 63, l15 = lane & 15, quad = lane >> 4;
  const int m0 = blockIdx.x * 32;
  const int wr = (wave >> 1) * 16, wc = (wave & 1) * 64;
  const int fl = *flag;
  const int srow = t >> 4, sc16 = t & 15;

  {  // stage x2 tile (32 x 128) + W1 chunk 0 via global_load_lds
#pragma unroll
    for (int p = 0; p < 2; p++) {
      int row = p * 16 + srow;
      int cs = sc16 ^ (row & 7);
      __builtin_amdgcn_global_load_lds(
          (const __attribute__((address_space(1))) void*)((const u16*)X2 +
                                                          (size_t)(m0 + row) * 128 +
                                                          cs * 8),
          (__attribute__((address_space(3))) void*)&sA[row * 128 + sc16 * 8], 16,
          0, 0);
    }
#pragma unroll
    for (int p = 0; p < 8; p++) {
      int row = p * 16 + srow;
      int cs = sc16 ^ (row & 7);
      __builtin_amdgcn_global_load_lds(
          (const __attribute__((address_space(1))) void*)((const u16*)W1 +
                                                          (size_t)row * 128 +
                                                          cs * 8),
          (__attribute__((address_space(3))) void*)&sB[row * 128 + sc16 * 8], 16,
          0, 0);
    }
  }
  __syncthreads();  // sA + first W1 chunk staged

  {  // ---- fused LN2 on sA, in place (8 threads/row, 16 cols each) ----
    int r = t >> 3, k = t & 7;
    bf16x8 c0 = *(const bf16x8*)&sA[r * 128 + (k * 2 + 0) * 8];
    bf16x8 c1 = *(const bf16x8*)&sA[r * 128 + (k * 2 + 1) * 8];
    float s = 0.f, sq = 0.f;
#pragma unroll
    for (int e = 0; e < 8; e++) {
      float f0 = (float)c0[e], f1 = (float)c1[e];
      s += f0 + f1;
      sq += f0 * f0 + f1 * f1;
    }
#pragma unroll
    for (int d = 1; d < 8; d <<= 1) {
      s += __shfl_xor(s, d);
      sq += __shfl_xor(sq, d);
    }
    float mean = s * (1.f / 128.f);
    float var = sq * (1.f / 128.f) - mean * mean;
    float rstd = rsqrtf(fmaxf(var, 0.f) + 1e-5f);
    // true col of chunk j is contiguous: ((k*2+j) ^ (r&7)) * 8 + e
    __syncthreads();  // all reads of sA done before in-place writes
#pragma unroll
    for (int j = 0; j < 2; j++) {
      int tc = ((k * 2 + j) ^ (r & 7)) * 8;
      bf16x8 gv = *(const bf16x8*)&G2[tc];
      bf16x8 bv = *(const bf16x8*)&B2n[tc];
      bf16x8 cv = j ? c1 : c0;
      bf16x8 ov;
#pragma unroll
      for (int e = 0; e < 8; e++)
        ov[e] = (bf16)(((float)cv[e] - mean) * rstd * (float)gv[e] + (float)bv[e]);
      *(bf16x8*)&sA[r * 128 + (k * 2 + j) * 8] = ov;
    }
  }
  __syncthreads();  // LN'd sA visible to all

  bf16x8 wreg[8];  // register-staged next W chunk (T14 split)

  // ---- mlp1: 4 n-chunks of 128, gelu into sH ----
#pragma unroll 1
  for (int nc = 0; nc < 4; nc++) {
    {  // issue next chunk's global loads into regs (hides under compute)
      const bf16* Wn = (nc < 3) ? W1 : W2;
      const int chunk = (nc < 3) ? nc + 1 : 0;
      const int wK = (nc < 3) ? 128 : 512;
#pragma unroll
      for (int p = 0; p < 8; p++) {
        int row = p * 16 + srow;
        int cs = sc16 ^ (row & 7);
        const u16* src = (const u16*)Wn +
                         (size_t)(wK == 128 ? (chunk * 128 + row) : row) * wK +
                         (wK == 128 ? 0 : chunk * 128) + cs * 8;
        wreg[p] = *(const bf16x8*)src;
      }
    }
    f32x4 acc1[4] = {};
#pragma unroll
    for (int ks = 0; ks < 4; ks++) {
      int arow = wr + l15;
      bf16x8 av = *(const bf16x8*)((const char*)sA + arow * 256 +
                                   (((ks * 4 + quad) ^ (arow & 7)) << 4));
      bf16x8 bv[4];
#pragma unroll
      for (int j = 0; j < 4; j++) {
        int row = wc + j * 16 + l15;
        bv[j] = *(const bf16x8*)((const char*)sB + row * 256 +
                                 (((ks * 4 + quad) ^ (row & 7)) << 4));
      }
#pragma unroll
      for (int j = 0; j < 4; j++)
        acc1[j] = __builtin_amdgcn_mfma_f32_16x16x32_bf16(av, bv[j], acc1[j], 0, 0, 0);
    }
#pragma unroll
    for (int j = 0; j < 4; j++) {
      int ncol = nc * 128 + wc + j * 16 + l15;
      float bj = (float)B1[ncol];
#pragma unroll
      for (int r = 0; r < 4; r++) {
        float v = acc1[j][r] + bj;
        float v2 = v * v;
        float u2 = v * (2.30220806f + 0.10294323f * v2);
        float e2 = exp2f(u2);
        v = v - v * __builtin_amdgcn_rcpf(e2 + 1.f);
        sH[(wr + quad * 4 + r) * 520 + ncol] = __builtin_bit_cast(u16, (bf16)v);
      }
    }
    __syncthreads();  // sB reads + sH writes done
#pragma unroll
    for (int p = 0; p < 8; p++) {
      int row = p * 16 + srow;
      *(bf16x8*)&sB[row * 128 + sc16 * 8] = wreg[p];
    }
    __syncthreads();  // staged
  }

  // ---- mlp2: contract K=512 from sH against reg-prefetched W2 chunks ----
  f32x4 acc2[4] = {};
#pragma unroll 1
  for (int kc = 0; kc < 4; kc++) {
    if (kc < 3) {  // issue next W2 k-slice loads into regs
      const int chunk = kc + 1;
#pragma unroll
      for (int p = 0; p < 8; p++) {
        int row = p * 16 + srow;
        int cs = sc16 ^ (row & 7);
        const u16* src =
            (const u16*)W2 + (size_t)row * 512 + chunk * 128 + cs * 8;
        wreg[p] = *(const bf16x8*)src;
      }
    }
#pragma unroll
    for (int ks = 0; ks < 4; ks++) {
      int arow = wr + l15;
      bf16x8 av = *(const bf16x8*)((const char*)sH + arow * 1040 +
                                   (kc * 128 + ks * 32 + quad * 8) * 2);
#pragma unroll
      for (int j = 0; j < 4; j++) {
        int row = wc + j * 16 + l15;
        bf16x8 bv = *(const bf16x8*)((const char*)sB + row * 256 +
                                     (((ks * 4 + quad) ^ (row & 7)) << 4));
        acc2[j] = __builtin_amdgcn_mfma_f32_16x16x32_bf16(av, bv, acc2[j], 0, 0, 0);
      }
    }
    if (kc < 3) {
      __syncthreads();  // sB reads done
#pragma unroll
      for (int p = 0; p < 8; p++) {
        int row = p * 16 + srow;
        *(bf16x8*)&sB[row * 128 + sc16 * 8] = wreg[p];
      }
      __syncthreads();  // staged
    }
  }
  // ---- epilogue: +b2 +resid(x2), flag-dispatched output dtype ----
#pragma unroll
  for (int j = 0; j < 4; j++) {
    int gn = wc + j * 16 + l15;
    float bj = (float)B2[gn];
#pragma unroll
    for (int r = 0; r < 4; r++) {
      int tok = m0 + wr + quad * 4 + r;
      size_t off = (size_t)tok * 128 + gn;
      float v = acc2[j][r] + bj + (float)X2[off];
      if (fl)
        ((bf16*)outv)[off] = (bf16)v;
      else
        ((float*)outv)[off] = v;
    }
  }
}

// ---------------------------------------------------------------------------
// Fused window attention, S^T formulation, exp2-domain, BARRIER-FREE K-loop.
// R13: both q-halves processed by ONE block (#pragma unroll 1 qh loop around
// the unchanged R10 kt-loop) — V^T staging + barrier amortized 2x, Q loads
// halved, grid 1024->512 = exactly 2 blocks/CU x 256 CU, single dispatch
// round. Per-half register state identical to R10 (no new live state across
// the kt loop — the four prefetch attempts R2/R4/R9/R11 all spilled; axis
// closed). Canaries: VGPR ~64-72, WRITE ~16.5 MB, LDS 65536.
// ---------------------------------------------------------------------------
__global__ __launch_bounds__(512, 4) void attn_k(const bf16* __restrict__ qkv,
                                                 const bf16* __restrict__ rpem,
                                                 bf16* __restrict__ att) {
  __shared__ __align__(16) bf16 sVt[32 * 512];   // V^T [d][key], swizzled, 32 KB
  __shared__ __align__(16) bf16 sP[8][32 * 64];  // per-wave P^T, swizzled, 32 KB
  const int t = threadIdx.x;
  const int p = blockIdx.x;  // [win_hi:4][head:2][win_lo:3] — 512 blocks
  const int win = ((p >> 5) << 3) | (p & 7);
  const int head = (p >> 3) & 3;
  const int wave = t >> 6, lane = t & 63, l15 = lane & 15, quad = lane >> 4;

  const int wd = win >> 6, wh = (win >> 3) & 7, ww = win & 7;
  const int type = ((wd == 1) << 2) | ((wh == 7) << 1) | (ww == 7);

  const size_t hw32 = (size_t)512 * 32;
  const bf16* qp = qkv + ((size_t)(0 * 4 + head) * 128 + win) * hw32;
  const bf16* kp = qkv + ((size_t)(1 * 4 + head) * 128 + win) * hw32;
  const bf16* vp = qkv + ((size_t)(2 * 4 + head) * 128 + win) * hw32;
  const bf16* rpeh = rpem + ((size_t)(type * 4 + head) << 18);

  {  // stage full V^T once (512 threads), XOR-swizzled u32 writes
    int kpi = t >> 3, dblk = (t & 7) * 4;
    char* sb = (char*)sVt;
#pragma unroll
    for (int kb = 0; kb < 4; kb++) {
      const bf16* v0 = vp + (size_t)(kb * 128 + 2 * kpi) * 32 + dblk;
      bf16x4 a = *(const bf16x4*)v0;
      bf16x4 b = *(const bf16x4*)(v0 + 32);
      int keyw = kb * 64 + kpi;
#pragma unroll
      for (int dd = 0; dd < 4; dd++) {
        int row = dblk + dd;
        unsigned wv = (unsigned)__builtin_bit_cast(u16, a[dd]) |
                      ((unsigned)__builtin_bit_cast(u16, b[dd]) << 16);
        *(unsigned*)(sb + ((row * 1024 + keyw * 4) ^ ((row & 7) << 4))) = wv;
      }
    }
  }

  // all-ones A-frag for the denominator MFMA
  bf16x8 ones;
#pragma unroll
  for (int e = 0; e < 8; e++) ones[e] = (bf16)1.0f;

  __syncthreads();  // the ONLY block-wide barrier

  char* pw = (char*)sP[wave];
  const char* sv = (const char*)sVt;
  const int swz = (l15 & 7) << 4;  // row-XOR (same for row and row+16)

#pragma unroll 1
  for (int qh = 0; qh < 2; qh++) {
    const int qbase = qh * 256 + wave * 32;
    // Q fragments (B operand): lane n=l15 -> query, k=quad*8+j -> d
    bf16x8 qa[2];
#pragma unroll
    for (int nt = 0; nt < 2; nt++)
      qa[nt] =
          *(const bf16x8*)(qp + (size_t)(qbase + nt * 16 + l15) * 32 + quad * 8);

    f32x4 O[2][2] = {};  // O^T tiles [dm][nt]
    f32x4 O2[2] = {};    // denominator tiles (all rows identical)

#pragma unroll 1
    for (int kt = 0; kt < 8; kt++) {
      // K frags + permuted rpe C-init (in-loop loads; 16 waves/CU hide them)
      bf16x8 kb[4];
      bf16x8 rv8[2][2];  // [nt][half: mt01|mt23]
#pragma unroll
      for (int mt = 0; mt < 4; mt++)
        kb[mt] = *(const bf16x8*)(kp + (size_t)(kt * 64 + mt * 16 + l15) * 32 +
                                  quad * 8);
#pragma unroll
      for (int nt = 0; nt < 2; nt++) {
        const bf16* rb =
            rpeh + ((size_t)(kt * 4 + quad) * 512 + (qbase + nt * 16 + l15)) * 16;
        rv8[nt][0] = *(const bf16x8*)rb;
        rv8[nt][1] = *(const bf16x8*)(rb + 8);
      }
      // S^T = K·Q^T with C initialized to fused rpe+mask (pure load)
      f32x4 S[4][2];
#pragma unroll
      for (int mt = 0; mt < 4; mt++)
#pragma unroll
        for (int nt = 0; nt < 2; nt++) {
          f32x4 c;
#pragma unroll
          for (int r = 0; r < 4; r++)
            c[r] = (float)rv8[nt][mt >> 1][(mt & 1) * 4 + r];
          S[mt][nt] =
              __builtin_amdgcn_mfma_f32_16x16x32_bf16(kb[mt], qa[nt], c, 0, 0, 0);
        }
      // exp2 + P store (swizzled b64 writes); denominator via MFMA
#pragma unroll
      for (int nt = 0; nt < 2; nt++)
#pragma unroll
        for (int mt = 0; mt < 4; mt++) {
          bf16x4 pv;
#pragma unroll
          for (int r = 0; r < 4; r++) pv[r] = (bf16)exp2f(S[mt][nt][r]);
          *(bf16x4*)(pw + (((nt * 16 + l15) * 128 + mt * 32 + quad * 8) ^ swz)) =
              pv;
        }
      // O^T += V^T · P ; denominator += ones · P  (sVt read-only; pw per-wave)
#pragma unroll
      for (int s = 0; s < 2; s++) {
        int vc = kt * 128 + s * 64 + quad * 16;  // byte col into V^T row
        int pc = s * 64 + quad * 16;             // byte col into P row
        bf16x8 va0 = *(const bf16x8*)(sv + ((l15 * 1024 + vc) ^ swz));
        bf16x8 va1 = *(const bf16x8*)(sv + (((16 + l15) * 1024 + vc) ^ swz));
        bf16x8 pb0 = *(const bf16x8*)(pw + ((l15 * 128 + pc) ^ swz));
        bf16x8 pb1 = *(const bf16x8*)(pw + (((16 + l15) * 128 + pc) ^ swz));
        O[0][0] = __builtin_amdgcn_mfma_f32_16x16x32_bf16(va0, pb0, O[0][0], 0, 0, 0);
        O[0][1] = __builtin_amdgcn_mfma_f32_16x16x32_bf16(va0, pb1, O[0][1], 0, 0, 0);
        O[1][0] = __builtin_amdgcn_mfma_f32_16x16x32_bf16(va1, pb0, O[1][0], 0, 0, 0);
        O[1][1] = __builtin_amdgcn_mfma_f32_16x16x32_bf16(va1, pb1, O[1][1], 0, 0, 0);
        O2[0] = __builtin_amdgcn_mfma_f32_16x16x32_bf16(ones, pb0, O2[0], 0, 0, 0);
        O2[1] = __builtin_amdgcn_mfma_f32_16x16x32_bf16(ones, pb1, O2[1], 0, 0, 0);
      }
    }
    // epilogue: denominator is in every lane of O2 (no shuffles needed)
#pragma unroll
    for (int nt = 0; nt < 2; nt++) {
      float inv = __builtin_amdgcn_rcpf(O2[nt][0]);
      int q = qbase + nt * 16 + l15;
#pragma unroll
      for (int dm = 0; dm < 2; dm++) {
        bf16x4 o;
#pragma unroll
        for (int r = 0; r < 4; r++) o[r] = (bf16)(O[dm][nt][r] * inv);
        *(bf16x4*)(att + ((size_t)win * 512 + q) * 128 + head * 32 + dm * 16 +
                   quad * 4) = o;
      }
    }
  }
}

// ---------------------------------------------------------------------------
extern "C" void kernel_launch(void* const* d_in, const int* in_sizes, int n_in,
                              void* d_out, int out_size, void* d_ws,
                              size_t ws_size, hipStream_t stream) {
  const int* rel_index = (const int*)d_in[2];
  char* w = (char*)d_ws;

  int* flag = (int*)w;
  bf16* qw_c = (bf16*)(w + (128ull << 10));
  bf16* pw_c = (bf16*)(w + (256ull << 10));
  bf16* w1_c = (bf16*)(w + (320ull << 10));
  bf16* w2_c = (bf16*)(w + (512ull << 10));
  bf16* qb_c = (bf16*)(w + (704ull << 10));
  bf16* pb_c = (bf16*)(w + (708ull << 10));
  bf16* g1_c = (bf16*)(w + (712ull << 10));
  bf16* b1n_c = (bf16*)(w + (716ull << 10));
  bf16* g2_c = (bf16*)(w + (720ull << 10));
  bf16* b2n_c = (bf16*)(w + (724ull << 10));
  bf16* mb1_c = (bf16*)(w + (728ull << 10));
  bf16* mb2_c = (bf16*)(w + (732ull << 10));
  bf16* xw = (bf16*)(w + (17ull << 20));    // [17,33) MB; reused: att
  bf16* qkvb = (bf16*)(w + (33ull << 20));  // [33,97) MB
  bf16* x2 = (bf16*)(w + (99ull << 20));    // [99,115) MB; rpem lives here
  bf16* rpem = x2;  // 16 MiB fused rpe+mask planes; dead before proj writes x2
  bf16* att = xw;

  sniff_k<<<1, 64, 0, stream>>>((const unsigned*)d_in[0], flag);
  canon_norm_k<<<1, 256, 0, stream>>>(d_in[8], d_in[9], g1_c, b1n_c, flag);

  ProArgs pa;
  pa.ridx = rel_index;
  pa.rbias = d_in[3];
  pa.rpem = rpem;
  pa.x = d_in[0];
  pa.g1 = g1_c;
  pa.b1n = b1n_c;
  pa.xw = xw;
  const int srcidx[12] = {4, 5, 6, 7, 8, 9, 10, 11, 12, 13, 14, 15};
  bf16* dsts[12] = {qw_c, qb_c, pw_c, pb_c, g1_c, b1n_c,
                    g2_c, b2n_c, w1_c, mb1_c, w2_c, mb2_c};
  for (int i = 0; i < 12; i++) {
    pa.csrc[i] = d_in[srcidx[i]];
    pa.cdst[i] = dsts[i];
    pa.cn[i] = in_sizes[srcidx[i]];
  }
  pro_k<<<27648, 256, 0, stream>>>(pa, flag);

  gemm_k<0, 32, 128, 384, 128><<<dim3(2048, 3), 256, 0, stream>>>(
      xw, qw_c, qb_c, qkvb, nullptr, flag);
  attn_k<<<512, 512, 0, stream>>>(qkvb, rpem, att);
  gemm_k<1, 32, 128, 128, 128><<<dim3(2048, 1), 256, 0, stream>>>(
      att, pw_c, pb_c, x2, d_in[0], flag);
  mlp_k<<<2048, 256, 0, stream>>>(x2, g2_c, b2n_c, w1_c, mb1_c, w2_c, mb2_c,
                                  d_out, flag);
}

// Round 14
// 374.215 us; speedup vs baseline: 1.0055x; 1.0055x over previous
//
#include <hip/hip_runtime.h>
#include <math.h>

typedef __bf16 bf16;
typedef __bf16 bf16x4 __attribute__((ext_vector_type(4)));
typedef __bf16 bf16x8 __attribute__((ext_vector_type(8)));
typedef float f32x4 __attribute__((ext_vector_type(4)));
typedef unsigned short u16;
typedef u16 u16x2 __attribute__((ext_vector_type(2)));

#define LOG2E 1.4426950408889634f

__device__ __forceinline__ float b2f(u16 b) {
  return (float)__builtin_bit_cast(bf16, b);
}

// ---------------------------------------------------------------------------
// dtype sniff (wave-parallel): packed-bf16 words have bits14..7 = bf16
// exponent (~[118,130]); f32 words have uniform mantissa bits there.
// ---------------------------------------------------------------------------
__global__ void sniff_k(const unsigned* __restrict__ xw_, int* __restrict__ flag) {
  int lane = threadIdx.x;  // 64 threads
  int c = 0;
#pragma unroll
  for (int j = 0; j < 4; j++) {
    unsigned e = (xw_[lane * 4 + j] >> 7) & 0xFFu;
    c += (e >= 100u && e <= 140u) ? 1 : 0;
  }
#pragma unroll
  for (int d = 1; d < 64; d <<= 1) c += __shfl_xor(c, d);
  if (lane == 0) *flag = (c >= 150) ? 1 : 0;
}

// ---------------------------------------------------------------------------
// Fused prologue (R14: ln1 segment removed — LN1 now fused into qkv_k):
//   [0,8192)      rpem: fused rpe+mask planes, PERMUTED layout, RAW rel_bias
//   [8192,11264)  canon: 12 small weight tensors -> bf16
// rpem plane[type][h] is [kt:8][quad:4][q:512][mt:4][r:4]; value =
// rel_bias[rel_index[q*512+m]][h]*log2e + (masked?-100*log2e:0).
// ---------------------------------------------------------------------------
struct ProArgs {
  const int* ridx;
  const void* rbias;
  bf16* rpem;
  const void* csrc[12];
  bf16* cdst[12];
  int cn[12];
};

__global__ __launch_bounds__(256) void pro_k(ProArgs a,
                                             const int* __restrict__ flag) {
  const int bx = blockIdx.x, tid = threadIdx.x;
  const int fl = *flag;
  if (bx < 8192) {  // ---- rpem ----
    int t = bx * 256 + tid;  // 2^21 threads, 4 m-values each
    int m0 = (t & 127) * 4, q = (t >> 7) & 511, h = (t >> 16) & 3, ty = t >> 18;
    int qd = q >> 6, qh = (q >> 3) & 7, qw = q & 7;
    int kt = m0 >> 6, mt = (m0 >> 4) & 3, quad = (m0 >> 2) & 3;
    int4 ri = *(const int4*)&a.ridx[q * 512 + m0];
    const int rv[4] = {ri.x, ri.y, ri.z, ri.w};
    bf16x4 o;
#pragma unroll
    for (int j = 0; j < 4; j++) {
      int m = m0 + j;
      int md = m >> 6, mh = (m >> 3) & 7, mw = m & 7;
      bool diff = ((ty & 4) && ((qd < 4) != (md < 4))) ||
                  ((ty & 2) && ((qh < 4) != (mh < 4))) ||
                  ((ty & 1) && ((qw < 4) != (mw < 4)));
      float bv = fl ? (float)((const bf16*)a.rbias)[rv[j] * 4 + h]
                    : ((const float*)a.rbias)[rv[j] * 4 + h];
      float v = bv * LOG2E;
      o[j] = (bf16)(v + (diff ? -144.2695041f : 0.f));
    }
    size_t out = ((size_t)(ty * 4 + h) << 18) +
                 (((size_t)(kt * 4 + quad) * 512 + q) * 16 + mt * 4);
    *(bf16x4*)&a.rpem[out] = o;
  } else {  // ---- canon ----
    int seg = bx - 8192;
    int ti = seg >> 8;
    int i = (seg & 255) * 256 + tid;
    if (i < a.cn[ti]) {
      if (fl)
        a.cdst[ti][i] = ((const bf16*)a.csrc[ti])[i];
      else
        a.cdst[ti][i] = (bf16)((const float*)a.csrc[ti])[i];
    }
  }
}

// ---------------------------------------------------------------------------
// qkv GEMM with FUSED LN1+roll in the A-staging (R14; same pattern as the
// measured-good LN2->mlp fusion): per 32-token tile, 8 threads/row load the
// ROLLED raw input (flag-dispatched dtype) into regs, 3-hop shfl row-reduce,
// normalize with g1/b1n, ds_write the XOR-swizzled A-tile. B staged via
// global_load_lds as before. One barrier. Kills the xw intermediate +
// pro_k's ln1 segment + the canon_norm_k launch.
// Epilogue: qkv head-major scatter, q pre-scaled by scale*log2e.
// ---------------------------------------------------------------------------
__global__ __launch_bounds__(256) void qkv_k(const void* __restrict__ X,
                                             const bf16* __restrict__ G1,
                                             const bf16* __restrict__ B1n,
                                             const bf16* __restrict__ B,
                                             const bf16* __restrict__ bias,
                                             bf16* __restrict__ outv,
                                             const int* __restrict__ flag) {
  __shared__ __align__(16) u16 SM[160 * 128];  // A rows 0..31, B rows 32..159
  const int t = threadIdx.x;
  const int wave = t >> 6, lane = t & 63, l15 = lane & 15, quad = lane >> 4;
  const int m0 = blockIdx.x * 32, n0 = blockIdx.y * 128;
  const int fl = *flag;
  f32x4 acc[4] = {};
  const int wr = (wave >> 1) * 16, wc = (wave & 1) * 64;
  const int srow = t >> 4, sc16 = t & 15;

  // ---- B staging (128 rows x 128 K) via global_load_lds, swizzled src ----
#pragma unroll
  for (int p = 0; p < 8; p++) {
    int row = 32 + p * 16 + srow;
    int cs = sc16 ^ (row & 7);
    __builtin_amdgcn_global_load_lds(
        (const __attribute__((address_space(1))) void*)((const u16*)B +
                                                        (size_t)(n0 + row - 32) *
                                                            128 +
                                                        cs * 8),
        (__attribute__((address_space(3))) void*)&SM[row * 128 + sc16 * 8], 16,
        0, 0);
  }

  {  // ---- A staging + fused LN1 (8 threads/row, 16 cols each) ----
    int row = t >> 3, k = t & 7;
    int tok = m0 + row;
    int win = tok >> 9, pos = tok & 511;
    int rd = (win >> 6) * 8 + (pos >> 6);
    int rh = ((win >> 3) & 7) * 8 + ((pos >> 3) & 7);
    int rw = (win & 7) * 8 + (pos & 7);
    int od = (rd + 4) & 15, oh = (rh + 4) & 63, ow = (rw + 4) & 63;
    size_t src = (size_t)((od * 64 + oh) * 64 + ow) * 128;
    float f[16];
    if (fl) {
      bf16x8 v0 = *(const bf16x8*)((const bf16*)X + src + (k * 2 + 0) * 8);
      bf16x8 v1 = *(const bf16x8*)((const bf16*)X + src + (k * 2 + 1) * 8);
#pragma unroll
      for (int e = 0; e < 8; e++) {
        f[e] = (float)v0[e];
        f[8 + e] = (float)v1[e];
      }
    } else {
      const float* xf = (const float*)X + src + k * 16;
      f32x4 a0 = *(const f32x4*)(xf + 0), a1 = *(const f32x4*)(xf + 4);
      f32x4 a2 = *(const f32x4*)(xf + 8), a3 = *(const f32x4*)(xf + 12);
#pragma unroll
      for (int e = 0; e < 4; e++) {
        f[e] = a0[e];
        f[4 + e] = a1[e];
        f[8 + e] = a2[e];
        f[12 + e] = a3[e];
      }
    }
    float s = 0.f, sq = 0.f;
#pragma unroll
    for (int e = 0; e < 16; e++) {
      s += f[e];
      sq += f[e] * f[e];
    }
#pragma unroll
    for (int d = 1; d < 8; d <<= 1) {
      s += __shfl_xor(s, d);
      sq += __shfl_xor(sq, d);
    }
    float mean = s * (1.f / 128.f);
    float var = sq * (1.f / 128.f) - mean * mean;
    float rstd = rsqrtf(fmaxf(var, 0.f) + 1e-5f);
#pragma unroll
    for (int j = 0; j < 2; j++) {
      int c = k * 2 + j;  // source chunk (true cols c*8..c*8+7)
      bf16x8 gv = *(const bf16x8*)&G1[c * 8];
      bf16x8 bv = *(const bf16x8*)&B1n[c * 8];
      bf16x8 ov;
#pragma unroll
      for (int e = 0; e < 8; e++)
        ov[e] = (bf16)((f[j * 8 + e] - mean) * rstd * (float)gv[e] + (float)bv[e]);
      *(bf16x8*)&SM[row * 128 + (c ^ (row & 7)) * 8] = ov;
    }
  }
  __syncthreads();  // A ds_writes + B global_load_lds drained

  // ---- MFMA: single K=128 stage ----
  const char* cur = (const char*)SM;
#pragma unroll
  for (int ks = 0; ks < 4; ks++) {
    int arow = wr + l15;
    bf16x8 a = *(const bf16x8*)(cur + arow * 256 +
                                (((ks * 4 + quad) ^ (arow & 7)) << 4));
#pragma unroll
    for (int j = 0; j < 4; j++) {
      int row = 32 + wc + j * 16 + l15;
      bf16x8 b = *(const bf16x8*)(cur + row * 256 +
                                  (((ks * 4 + quad) ^ (row & 7)) << 4));
      acc[j] = __builtin_amdgcn_mfma_f32_16x16x32_bf16(a, b, acc[j], 0, 0, 0);
    }
  }
  // ---- epilogue: qkv head-major scatter; q scaled by scale*log2e ----
  const float qscale = 0.17677669529663687f * LOG2E;
#pragma unroll
  for (int r = 0; r < 4; r++) {
    int tok = m0 + wr + quad * 4 + r;
    int win = tok >> 9, pos = tok & 511;
#pragma unroll
    for (int j = 0; j < 4; j++) {
      int gn = n0 + wc + j * 16 + l15;
      float v = acc[j][r] + (float)bias[gn];
      int tensor = gn >> 7, c = gn & 127, head = c >> 5, d = c & 31;
      if (tensor == 0) v *= qscale;
      size_t off = ((((size_t)tensor * 4 + head) * 128 + win) * 512 + pos) * 32 + d;
      outv[off] = (bf16)v;
    }
  }
}

// ---------------------------------------------------------------------------
// proj GEMM: BM=32, BK=128 single-stage, LDS 40 KB -> 4 blocks/CU.
// global_load_lds width=16, swizzled. win-rev+roll+RAW-resid epilogue.
// ---------------------------------------------------------------------------
__global__ __launch_bounds__(256) void proj_k(const bf16* __restrict__ A,
                                              const bf16* __restrict__ B,
                                              const bf16* __restrict__ bias,
                                              bf16* __restrict__ outv,
                                              const void* __restrict__ residv,
                                              const int* __restrict__ flag) {
  __shared__ __align__(16) u16 SM[160 * 128];
  const int t = threadIdx.x;
  const int wave = t >> 6, lane = t & 63, l15 = lane & 15, quad = lane >> 4;
  const int m0 = blockIdx.x * 32, n0 = 0;
  const int fl = *flag;
  f32x4 acc[4] = {};
  const int wr = (wave >> 1) * 16, wc = (wave & 1) * 64;
  const int srow = t >> 4, sc16 = t & 15;

#pragma unroll
  for (int p = 0; p < 10; p++) {
    int row = p * 16 + srow;
    int cs = sc16 ^ (row & 7);
    const u16* src;
    if (row < 32)
      src = (const u16*)A + (size_t)(m0 + row) * 128 + cs * 8;
    else
      src = (const u16*)B + (size_t)(n0 + row - 32) * 128 + cs * 8;
    __builtin_amdgcn_global_load_lds(
        (const __attribute__((address_space(1))) void*)src,
        (__attribute__((address_space(3))) void*)&SM[row * 128 + sc16 * 8], 16,
        0, 0);
  }
  __syncthreads();

  const char* cur = (const char*)SM;
#pragma unroll
  for (int ks = 0; ks < 4; ks++) {
    int arow = wr + l15;
    bf16x8 a = *(const bf16x8*)(cur + arow * 256 +
                                (((ks * 4 + quad) ^ (arow & 7)) << 4));
#pragma unroll
    for (int j = 0; j < 4; j++) {
      int row = 32 + wc + j * 16 + l15;
      bf16x8 b = *(const bf16x8*)(cur + row * 256 +
                                  (((ks * 4 + quad) ^ (row & 7)) << 4));
      acc[j] = __builtin_amdgcn_mfma_f32_16x16x32_bf16(a, b, acc[j], 0, 0, 0);
    }
  }
#pragma unroll
  for (int r = 0; r < 4; r++) {
    int tok = m0 + wr + quad * 4 + r;
    int win = tok >> 9, pos = tok & 511;
    int rd = (win >> 6) * 8 + (pos >> 6);
    int rh = ((win >> 3) & 7) * 8 + ((pos >> 3) & 7);
    int rw = (win & 7) * 8 + (pos & 7);
    int od = (rd + 4) & 15, oh = (rh + 4) & 63, ow = (rw + 4) & 63;
    size_t obase = (size_t)((od * 64 + oh) * 64 + ow) * 128;
#pragma unroll
    for (int j = 0; j < 4; j++) {
      int gn = wc + j * 16 + l15;
      float v = acc[j][r] + (float)bias[gn];
      float rs = fl ? (float)((const bf16*)residv)[obase + gn]
                    : ((const float*)residv)[obase + gn];
      v += rs;
      outv[obase + gn] = (bf16)v;
    }
  }
}

// ---------------------------------------------------------------------------
// Fused MLP (R13-kept): R10 structure + T14 register-staged W prefetch +
// fused LN2 in the prologue. gelu(h1) lives in sH (a1 never touches HBM).
// ---------------------------------------------------------------------------
__global__ __launch_bounds__(256) void mlp_k(const bf16* __restrict__ X2,
                                             const bf16* __restrict__ G2,
                                             const bf16* __restrict__ B2n,
                                             const bf16* __restrict__ W1,
                                             const bf16* __restrict__ B1,
                                             const bf16* __restrict__ W2,
                                             const bf16* __restrict__ B2,
                                             void* __restrict__ outv,
                                             const int* __restrict__ flag) {
  __shared__ __align__(16) u16 sA[32 * 128];   // LN(x2) tile, swizzled, 8 KB
  __shared__ __align__(16) u16 sB[128 * 128];  // w1/w2 chunk, swizzled, 32 KB
  __shared__ __align__(16) u16 sH[32 * 520];   // gelu(h1) tile, padded, 33 KB
  const int t = threadIdx.x;
  const int wave = t >> 6, lane = t & 63, l15 = lane & 15, quad = lane >> 4;
  const int m0 = blockIdx.x * 32;
  const int wr = (wave >> 1) * 16, wc = (wave & 1) * 64;
  const int fl = *flag;
  const int srow = t >> 4, sc16 = t & 15;

  {  // stage x2 tile (32 x 128) + W1 chunk 0 via global_load_lds
#pragma unroll
    for (int p = 0; p < 2; p++) {
      int row = p * 16 + srow;
      int cs = sc16 ^ (row & 7);
      __builtin_amdgcn_global_load_lds(
          (const __attribute__((address_space(1))) void*)((const u16*)X2 +
                                                          (size_t)(m0 + row) * 128 +
                                                          cs * 8),
          (__attribute__((address_space(3))) void*)&sA[row * 128 + sc16 * 8], 16,
          0, 0);
    }
#pragma unroll
    for (int p = 0; p < 8; p++) {
      int row = p * 16 + srow;
      int cs = sc16 ^ (row & 7);
      __builtin_amdgcn_global_load_lds(
          (const __attribute__((address_space(1))) void*)((const u16*)W1 +
                                                          (size_t)row * 128 +
                                                          cs * 8),
          (__attribute__((address_space(3))) void*)&sB[row * 128 + sc16 * 8], 16,
          0, 0);
    }
  }
  __syncthreads();  // sA + first W1 chunk staged

  {  // ---- fused LN2 on sA, in place (8 threads/row, 16 cols each) ----
    int r = t >> 3, k = t & 7;
    bf16x8 c0 = *(const bf16x8*)&sA[r * 128 + (k * 2 + 0) * 8];
    bf16x8 c1 = *(const bf16x8*)&sA[r * 128 + (k * 2 + 1) * 8];
    float s = 0.f, sq = 0.f;
#pragma unroll
    for (int e = 0; e < 8; e++) {
      float f0 = (float)c0[e], f1 = (float)c1[e];
      s += f0 + f1;
      sq += f0 * f0 + f1 * f1;
    }
#pragma unroll
    for (int d = 1; d < 8; d <<= 1) {
      s += __shfl_xor(s, d);
      sq += __shfl_xor(sq, d);
    }
    float mean = s * (1.f / 128.f);
    float var = sq * (1.f / 128.f) - mean * mean;
    float rstd = rsqrtf(fmaxf(var, 0.f) + 1e-5f);
    __syncthreads();  // all reads of sA done before in-place writes
#pragma unroll
    for (int j = 0; j < 2; j++) {
      int tc = ((k * 2 + j) ^ (r & 7)) * 8;
      bf16x8 gv = *(const bf16x8*)&G2[tc];
      bf16x8 bv = *(const bf16x8*)&B2n[tc];
      bf16x8 cv = j ? c1 : c0;
      bf16x8 ov;
#pragma unroll
      for (int e = 0; e < 8; e++)
        ov[e] = (bf16)(((float)cv[e] - mean) * rstd * (float)gv[e] + (float)bv[e]);
      *(bf16x8*)&sA[r * 128 + (k * 2 + j) * 8] = ov;
    }
  }
  __syncthreads();  // LN'd sA visible to all

  bf16x8 wreg[8];  // register-staged next W chunk (T14 split)

  // ---- mlp1: 4 n-chunks of 128, gelu into sH ----
#pragma unroll 1
  for (int nc = 0; nc < 4; nc++) {
    {  // issue next chunk's global loads into regs (hides under compute)
      const bf16* Wn = (nc < 3) ? W1 : W2;
      const int chunk = (nc < 3) ? nc + 1 : 0;
      const int wK = (nc < 3) ? 128 : 512;
#pragma unroll
      for (int p = 0; p < 8; p++) {
        int row = p * 16 + srow;
        int cs = sc16 ^ (row & 7);
        const u16* src = (const u16*)Wn +
                         (size_t)(wK == 128 ? (chunk * 128 + row) : row) * wK +
                         (wK == 128 ? 0 : chunk * 128) + cs * 8;
        wreg[p] = *(const bf16x8*)src;
      }
    }
    f32x4 acc1[4] = {};
#pragma unroll
    for (int ks = 0; ks < 4; ks++) {
      int arow = wr + l15;
      bf16x8 av = *(const bf16x8*)((const char*)sA + arow * 256 +
                                   (((ks * 4 + quad) ^ (arow & 7)) << 4));
      bf16x8 bv[4];
#pragma unroll
      for (int j = 0; j < 4; j++) {
        int row = wc + j * 16 + l15;
        bv[j] = *(const bf16x8*)((const char*)sB + row * 256 +
                                 (((ks * 4 + quad) ^ (row & 7)) << 4));
      }
#pragma unroll
      for (int j = 0; j < 4; j++)
        acc1[j] = __builtin_amdgcn_mfma_f32_16x16x32_bf16(av, bv[j], acc1[j], 0, 0, 0);
    }
#pragma unroll
    for (int j = 0; j < 4; j++) {
      int ncol = nc * 128 + wc + j * 16 + l15;
      float bj = (float)B1[ncol];
#pragma unroll
      for (int r = 0; r < 4; r++) {
        float v = acc1[j][r] + bj;
        float v2 = v * v;
        float u2 = v * (2.30220806f + 0.10294323f * v2);
        float e2 = exp2f(u2);
        v = v - v * __builtin_amdgcn_rcpf(e2 + 1.f);
        sH[(wr + quad * 4 + r) * 520 + ncol] = __builtin_bit_cast(u16, (bf16)v);
      }
    }
    __syncthreads();  // sB reads + sH writes done
#pragma unroll
    for (int p = 0; p < 8; p++) {
      int row = p * 16 + srow;
      *(bf16x8*)&sB[row * 128 + sc16 * 8] = wreg[p];
    }
    __syncthreads();  // staged
  }

  // ---- mlp2: contract K=512 from sH against reg-prefetched W2 chunks ----
  f32x4 acc2[4] = {};
#pragma unroll 1
  for (int kc = 0; kc < 4; kc++) {
    if (kc < 3) {  // issue next W2 k-slice loads into regs
      const int chunk = kc + 1;
#pragma unroll
      for (int p = 0; p < 8; p++) {
        int row = p * 16 + srow;
        int cs = sc16 ^ (row & 7);
        const u16* src =
            (const u16*)W2 + (size_t)row * 512 + chunk * 128 + cs * 8;
        wreg[p] = *(const bf16x8*)src;
      }
    }
#pragma unroll
    for (int ks = 0; ks < 4; ks++) {
      int arow = wr + l15;
      bf16x8 av = *(const bf16x8*)((const char*)sH + arow * 1040 +
                                   (kc * 128 + ks * 32 + quad * 8) * 2);
#pragma unroll
      for (int j = 0; j < 4; j++) {
        int row = wc + j * 16 + l15;
        bf16x8 bv = *(const bf16x8*)((const char*)sB + row * 256 +
                                     (((ks * 4 + quad) ^ (row & 7)) << 4));
        acc2[j] = __builtin_amdgcn_mfma_f32_16x16x32_bf16(av, bv, acc2[j], 0, 0, 0);
      }
    }
    if (kc < 3) {
      __syncthreads();  // sB reads done
#pragma unroll
      for (int p = 0; p < 8; p++) {
        int row = p * 16 + srow;
        *(bf16x8*)&sB[row * 128 + sc16 * 8] = wreg[p];
      }
      __syncthreads();  // staged
    }
  }
  // ---- epilogue: +b2 +resid(x2), flag-dispatched output dtype ----
#pragma unroll
  for (int j = 0; j < 4; j++) {
    int gn = wc + j * 16 + l15;
    float bj = (float)B2[gn];
#pragma unroll
    for (int r = 0; r < 4; r++) {
      int tok = m0 + wr + quad * 4 + r;
      size_t off = (size_t)tok * 128 + gn;
      float v = acc2[j][r] + bj + (float)X2[off];
      if (fl)
        ((bf16*)outv)[off] = (bf16)v;
      else
        ((float*)outv)[off] = v;
    }
  }
}

// ---------------------------------------------------------------------------
// Fused window attention (R13-kept): both q-halves in one block, 8-wave
// shared-V (64 KB LDS, 2 blocks/CU), per-wave sP, denominator on the MFMA
// pipe, XOR-swizzled LDS, permuted-rpem b128 C-init, #pragma unroll 1.
// NO register prefetch (R2/R4/R9/R11 all spilled; axis closed).
// ---------------------------------------------------------------------------
__global__ __launch_bounds__(512, 4) void attn_k(const bf16* __restrict__ qkv,
                                                 const bf16* __restrict__ rpem,
                                                 bf16* __restrict__ att) {
  __shared__ __align__(16) bf16 sVt[32 * 512];   // V^T [d][key], swizzled, 32 KB
  __shared__ __align__(16) bf16 sP[8][32 * 64];  // per-wave P^T, swizzled, 32 KB
  const int t = threadIdx.x;
  const int p = blockIdx.x;  // [win_hi:4][head:2][win_lo:3] — 512 blocks
  const int win = ((p >> 5) << 3) | (p & 7);
  const int head = (p >> 3) & 3;
  const int wave = t >> 6, lane = t & 63, l15 = lane & 15, quad = lane >> 4;

  const int wd = win >> 6, wh = (win >> 3) & 7, ww = win & 7;
  const int type = ((wd == 1) << 2) | ((wh == 7) << 1) | (ww == 7);

  const size_t hw32 = (size_t)512 * 32;
  const bf16* qp = qkv + ((size_t)(0 * 4 + head) * 128 + win) * hw32;
  const bf16* kp = qkv + ((size_t)(1 * 4 + head) * 128 + win) * hw32;
  const bf16* vp = qkv + ((size_t)(2 * 4 + head) * 128 + win) * hw32;
  const bf16* rpeh = rpem + ((size_t)(type * 4 + head) << 18);

  {  // stage full V^T once (512 threads), XOR-swizzled u32 writes
    int kpi = t >> 3, dblk = (t & 7) * 4;
    char* sb = (char*)sVt;
#pragma unroll
    for (int kb = 0; kb < 4; kb++) {
      const bf16* v0 = vp + (size_t)(kb * 128 + 2 * kpi) * 32 + dblk;
      bf16x4 a = *(const bf16x4*)v0;
      bf16x4 b = *(const bf16x4*)(v0 + 32);
      int keyw = kb * 64 + kpi;
#pragma unroll
      for (int dd = 0; dd < 4; dd++) {
        int row = dblk + dd;
        unsigned wv = (unsigned)__builtin_bit_cast(u16, a[dd]) |
                      ((unsigned)__builtin_bit_cast(u16, b[dd]) << 16);
        *(unsigned*)(sb + ((row * 1024 + keyw * 4) ^ ((row & 7) << 4))) = wv;
      }
    }
  }

  // all-ones A-frag for the denominator MFMA
  bf16x8 ones;
#pragma unroll
  for (int e = 0; e < 8; e++) ones[e] = (bf16)1.0f;

  __syncthreads();  // the ONLY block-wide barrier

  char* pw = (char*)sP[wave];
  const char* sv = (const char*)sVt;
  const int swz = (l15 & 7) << 4;  // row-XOR (same for row and row+16)

#pragma unroll 1
  for (int qh = 0; qh < 2; qh++) {
    const int qbase = qh * 256 + wave * 32;
    // Q fragments (B operand): lane n=l15 -> query, k=quad*8+j -> d
    bf16x8 qa[2];
#pragma unroll
    for (int nt = 0; nt < 2; nt++)
      qa[nt] =
          *(const bf16x8*)(qp + (size_t)(qbase + nt * 16 + l15) * 32 + quad * 8);

    f32x4 O[2][2] = {};  // O^T tiles [dm][nt]
    f32x4 O2[2] = {};    // denominator tiles (all rows identical)

#pragma unroll 1
    for (int kt = 0; kt < 8; kt++) {
      // K frags + permuted rpe C-init (in-loop loads; 16 waves/CU hide them)
      bf16x8 kb[4];
      bf16x8 rv8[2][2];  // [nt][half: mt01|mt23]
#pragma unroll
      for (int mt = 0; mt < 4; mt++)
        kb[mt] = *(const bf16x8*)(kp + (size_t)(kt * 64 + mt * 16 + l15) * 32 +
                                  quad * 8);
#pragma unroll
      for (int nt = 0; nt < 2; nt++) {
        const bf16* rb =
            rpeh + ((size_t)(kt * 4 + quad) * 512 + (qbase + nt * 16 + l15)) * 16;
        rv8[nt][0] = *(const bf16x8*)rb;
        rv8[nt][1] = *(const bf16x8*)(rb + 8);
      }
      // S^T = K·Q^T with C initialized to fused rpe+mask (pure load)
      f32x4 S[4][2];
#pragma unroll
      for (int mt = 0; mt < 4; mt++)
#pragma unroll
        for (int nt = 0; nt < 2; nt++) {
          f32x4 c;
#pragma unroll
          for (int r = 0; r < 4; r++)
            c[r] = (float)rv8[nt][mt >> 1][(mt & 1) * 4 + r];
          S[mt][nt] =
              __builtin_amdgcn_mfma_f32_16x16x32_bf16(kb[mt], qa[nt], c, 0, 0, 0);
        }
      // exp2 + P store (swizzled b64 writes); denominator via MFMA
#pragma unroll
      for (int nt = 0; nt < 2; nt++)
#pragma unroll
        for (int mt = 0; mt < 4; mt++) {
          bf16x4 pv;
#pragma unroll
          for (int r = 0; r < 4; r++) pv[r] = (bf16)exp2f(S[mt][nt][r]);
          *(bf16x4*)(pw + (((nt * 16 + l15) * 128 + mt * 32 + quad * 8) ^ swz)) =
              pv;
        }
      // O^T += V^T · P ; denominator += ones · P  (sVt read-only; pw per-wave)
#pragma unroll
      for (int s = 0; s < 2; s++) {
        int vc = kt * 128 + s * 64 + quad * 16;  // byte col into V^T row
        int pc = s * 64 + quad * 16;             // byte col into P row
        bf16x8 va0 = *(const bf16x8*)(sv + ((l15 * 1024 + vc) ^ swz));
        bf16x8 va1 = *(const bf16x8*)(sv + (((16 + l15) * 1024 + vc) ^ swz));
        bf16x8 pb0 = *(const bf16x8*)(pw + ((l15 * 128 + pc) ^ swz));
        bf16x8 pb1 = *(const bf16x8*)(pw + (((16 + l15) * 128 + pc) ^ swz));
        O[0][0] = __builtin_amdgcn_mfma_f32_16x16x32_bf16(va0, pb0, O[0][0], 0, 0, 0);
        O[0][1] = __builtin_amdgcn_mfma_f32_16x16x32_bf16(va0, pb1, O[0][1], 0, 0, 0);
        O[1][0] = __builtin_amdgcn_mfma_f32_16x16x32_bf16(va1, pb0, O[1][0], 0, 0, 0);
        O[1][1] = __builtin_amdgcn_mfma_f32_16x16x32_bf16(va1, pb1, O[1][1], 0, 0, 0);
        O2[0] = __builtin_amdgcn_mfma_f32_16x16x32_bf16(ones, pb0, O2[0], 0, 0, 0);
        O2[1] = __builtin_amdgcn_mfma_f32_16x16x32_bf16(ones, pb1, O2[1], 0, 0, 0);
      }
    }
    // epilogue: denominator is in every lane of O2 (no shuffles needed)
#pragma unroll
    for (int nt = 0; nt < 2; nt++) {
      float inv = __builtin_amdgcn_rcpf(O2[nt][0]);
      int q = qbase + nt * 16 + l15;
#pragma unroll
      for (int dm = 0; dm < 2; dm++) {
        bf16x4 o;
#pragma unroll
        for (int r = 0; r < 4; r++) o[r] = (bf16)(O[dm][nt][r] * inv);
        *(bf16x4*)(att + ((size_t)win * 512 + q) * 128 + head * 32 + dm * 16 +
                   quad * 4) = o;
      }
    }
  }
}

// ---------------------------------------------------------------------------
extern "C" void kernel_launch(void* const* d_in, const int* in_sizes, int n_in,
                              void* d_out, int out_size, void* d_ws,
                              size_t ws_size, hipStream_t stream) {
  const int* rel_index = (const int*)d_in[2];
  char* w = (char*)d_ws;

  int* flag = (int*)w;
  bf16* qw_c = (bf16*)(w + (128ull << 10));
  bf16* pw_c = (bf16*)(w + (256ull << 10));
  bf16* w1_c = (bf16*)(w + (320ull << 10));
  bf16* w2_c = (bf16*)(w + (512ull << 10));
  bf16* qb_c = (bf16*)(w + (704ull << 10));
  bf16* pb_c = (bf16*)(w + (708ull << 10));
  bf16* g1_c = (bf16*)(w + (712ull << 10));
  bf16* b1n_c = (bf16*)(w + (716ull << 10));
  bf16* g2_c = (bf16*)(w + (720ull << 10));
  bf16* b2n_c = (bf16*)(w + (724ull << 10));
  bf16* mb1_c = (bf16*)(w + (728ull << 10));
  bf16* mb2_c = (bf16*)(w + (732ull << 10));
  bf16* xw = (bf16*)(w + (17ull << 20));    // [17,33) MB; att lives here
  bf16* qkvb = (bf16*)(w + (33ull << 20));  // [33,97) MB
  bf16* x2 = (bf16*)(w + (99ull << 20));    // [99,115) MB; rpem lives here
  bf16* rpem = x2;  // 16 MiB fused rpe+mask planes; dead before proj writes x2
  bf16* att = xw;

  sniff_k<<<1, 64, 0, stream>>>((const unsigned*)d_in[0], flag);

  ProArgs pa;
  pa.ridx = rel_index;
  pa.rbias = d_in[3];
  pa.rpem = rpem;
  const int srcidx[12] = {4, 5, 6, 7, 8, 9, 10, 11, 12, 13, 14, 15};
  bf16* dsts[12] = {qw_c, qb_c, pw_c, pb_c, g1_c, b1n_c,
                    g2_c, b2n_c, w1_c, mb1_c, w2_c, mb2_c};
  for (int i = 0; i < 12; i++) {
    pa.csrc[i] = d_in[srcidx[i]];
    pa.cdst[i] = dsts[i];
    pa.cn[i] = in_sizes[srcidx[i]];
  }
  pro_k<<<11264, 256, 0, stream>>>(pa, flag);

  // qkv GEMM with fused LN1+roll A-staging (reads RAW input)
  qkv_k<<<dim3(2048, 3), 256, 0, stream>>>(d_in[0], g1_c, b1n_c, qw_c, qb_c,
                                           qkvb, flag);
  attn_k<<<512, 512, 0, stream>>>(qkvb, rpem, att);
  proj_k<<<2048, 256, 0, stream>>>(att, pw_c, pb_c, x2, d_in[0], flag);
  mlp_k<<<2048, 256, 0, stream>>>(x2, g2_c, b2n_c, w1_c, mb1_c, w2_c, mb2_c,
                                  d_out, flag);
}